// Round 17
// baseline (202.212 us; speedup 1.0000x reference)
//
#include <hip/hip_runtime.h>
#include <math.h>

typedef _Float16 f16x8 __attribute__((ext_vector_type(8)));
typedef _Float16 f16x4 __attribute__((ext_vector_type(4)));
typedef _Float16 f16x2 __attribute__((ext_vector_type(2)));
typedef float    f32x4 __attribute__((ext_vector_type(4)));
// may_alias views for the unioned LDS region (state-frags <-> per-wave fp16 zbuf)
typedef f16x8 f16x8_a __attribute__((may_alias));
typedef f16x4 f16x4_a __attribute__((may_alias));
typedef f32x4 f32x4_a __attribute__((may_alias));

#define MSAMP 8       // samples per block; state-rows: r = s*8 + m, r 56..63 pad

__device__ __forceinline__ float tanh_fast(float x) {
    // 1 - 2/(exp(2x)+1); ~1e-6 abs error (verified R7..R16)
    const float e = __expf(2.0f * x);
    return 1.0f - 2.0f * __builtin_amdgcn_rcpf(e + 1.0f);
}

__device__ __forceinline__ f16x2 pkrtz(float a, float b) {
    return __builtin_bit_cast(f16x2, __builtin_amdgcn_cvt_pkrtz(a, b));
}
__device__ __forceinline__ f16x4 cat2(f16x2 a, f16x2 b) {
    return __builtin_shufflevector(a, b, 0, 1, 2, 3);
}
__device__ __forceinline__ f16x4 pack4(const float* v) {
    return cat2(pkrtz(v[0], v[1]), pkrtz(v[2], v[3]));
}

// W swizzle, single fp16 (UNCHANGED from R12..R16):
//   off(l,kt,jt,lane,jj) = ((l*8+kt)*16+jt)*512 + lane*8 + jj ; per-l stride 65536
__global__ void prep_w(const float* __restrict__ W1, const float* __restrict__ W2,
                       const float* __restrict__ W3, _Float16* __restrict__ wsw) {
    const int tid = blockIdx.x * 256 + threadIdx.x;      // 3*8*16*64*8 = 196608
    if (tid >= 3 * 8 * 16 * 64 * 8) return;
    const int j    = tid & 7;
    const int lane = (tid >> 3) & 63;
    const int nt   = (tid >> 9) & 15;
    const int kt   = (tid >> 13) & 7;
    const int l    = tid >> 16;
    const float* W = (l == 0) ? W1 : (l == 1) ? W2 : W3;
    const int k = kt * 32 + (lane >> 4) * 8 + j;
    const int n = nt * 16 + (lane & 15);
    wsw[((size_t)((l * 8 + kt) * 16 + nt)) * 512 + lane * 8 + j] = (_Float16)W[k * 256 + n];
}

// 512-thread / 8-wave variant (R16 structure, tile halved per wave):
// Wave wv owns jt pair {2wv, 2wv+1} (units wv*32..+31) -> acc[2][4] = 32 AGPRs;
// launch_bounds(512,4): cap 128 regs, 2 blocks x 8 waves = 16 waves/CU.
// Wave's coupled units = B k-slice {wv} (4 KB) -> per-wave fp16 zbuf aliases it:
//   zh(r, jl) = wv*2048 + r*32 + ((jl + 4*(r&7)) & 31)   [halfword units]
// K rotation kt=(wv+1+i)&7, own slice last, barrier inside K-loop at i==7.
// Coupling: 4 units/lane (qd = lane>>3, m = lane&7) — 64 full tasks, z-reads
// collapse to 7 b64 (rotation is s-invariant). Butterfly over qd via shfl_xor.
__global__ __launch_bounds__(512, 4)
void pinn_mfma(const float* __restrict__ X,
               const float* __restrict__ W0, const float* __restrict__ b0,
               const float* __restrict__ b1, const float* __restrict__ b2,
               const float* __restrict__ b3,
               const float* __restrict__ W4, const float* __restrict__ b4,
               const float* __restrict__ lb, const float* __restrict__ ub,
               const _Float16* __restrict__ wsw,
               float* __restrict__ out, int N)
{
    __shared__ __attribute__((aligned(16))) char  smem[32768];   // state frags / zbuf
    __shared__ __attribute__((aligned(16))) float redw[896];     // [ch*56+s*8+m][wv 0..7]
    f16x8_a*  BV = (f16x8_a*)smem;                // vec idx = (kt*4+rt)*64 + lane
    _Float16* Bh = (_Float16*)smem;               // halfword view (writes / zbuf)

    const int t    = threadIdx.x;
    const int s0   = blockIdx.x * MSAMP;
    const int wv   = t >> 6, lane = t & 63;
    const int q    = lane >> 4, c = lane & 15;    // C/D + B-frag coords
    const int qd   = lane >> 3, m = lane & 7;     // coupling task (unit quad, sample)
    const f16x8 zvec8 = {};

    float lbv[3], cv[3];
    #pragma unroll
    for (int k = 0; k < 3; ++k) { lbv[k] = lb[k]; cv[k] = 2.0f / (ub[k] - lbv[k]); }

    // ---------------- layer 0: inputs -> first hidden states (B frags) ----------------
    {
        const int qd4 = t >> 3, m0 = t & 7;       // unit quad qd4*4..+3, sample m0
        const int n = s0 + m0;
        float x0 = 0.f, x1 = 0.f, x2 = 0.f;
        if (n < N) { x0 = X[n*3+0]; x1 = X[n*3+1]; x2 = X[n*3+2]; }
        const float h0 = cv[0]*(x0 - lbv[0]) - 1.0f;
        const float h1 = cv[1]*(x1 - lbv[1]) - 1.0f;
        const float h2 = cv[2]*(x2 - lbv[2]) - 1.0f;

        float w0v[4], w1v[4], w2v[4], bv[4];
        *(f32x4*)w0v = *(const f32x4*)&W0[0*256 + qd4*4];
        *(f32x4*)w1v = *(const f32x4*)&W0[1*256 + qd4*4];
        *(f32x4*)w2v = *(const f32x4*)&W0[2*256 + qd4*4];
        *(f32x4*)bv  = *(const f32x4*)&b0[qd4*4];

        float st[7][4];
        #pragma unroll
        for (int jj = 0; jj < 4; ++jj) {
            const float zH  = h0*w0v[jj] + h1*w1v[jj] + h2*w2v[jj] + bv[jj];
            const float zt0 = cv[0]*w0v[jj];
            const float zt1 = cv[1]*w1v[jj];
            const float zt2 = cv[2]*w2v[jj];
            const float h   = tanh_fast(zH);
            const float dd  = 1.0f - h*h;
            const float qq  = -2.0f * h * (zt0 + zt1 + zt2);
            st[0][jj] = h;
            st[1][jj] = dd * zt0; st[2][jj] = dd * zt1; st[3][jj] = dd * zt2;
            st[4][jj] = dd * (qq*zt0); st[5][jj] = dd * (qq*zt1); st[6][jj] = dd * (qq*zt2);
        }
        #pragma unroll
        for (int s = 0; s < 7; ++s) {
            const int r = s*8 + m0;
            const int vid = ((qd4>>3)*4 + (r>>4))*64 + ((qd4>>1)&3)*16 + (r & 15);
            *(f16x4_a*)&Bh[vid*8 + (qd4&1)*4] = pack4(&st[s][0]);
        }
    }
    // zero pad rows r=56..63: 8 kt x 4 lq x 8 r = 256 b128 vectors
    if (t < 256) {
        const int vid = ((t>>5)*4 + 3)*64 + ((t>>3)&3)*16 + 8 + (t&7);
        BV[vid] = zvec8;
    }
    __syncthreads();

    // ---------------- hidden layers: rotated-K GEMM + wave-local coupling ----------------
    #pragma unroll 1
    for (int l = 0; l < 3; ++l) {
        const _Float16* __restrict__ Wb = wsw + (size_t)l * 65536;

        f32x4 acc[2][4];   // [mtj][rt]
        #pragma unroll
        for (int a = 0; a < 2; ++a)
            #pragma unroll
            for (int b = 0; b < 4; ++b) acc[a][b] = (f32x4){0.f, 0.f, 0.f, 0.f};

        #pragma unroll
        for (int i = 0; i < 8; ++i) {
            if (i == 7) __syncthreads();   // all foreign-slice reads (i<=6, every wave)
                                           // done before any wave's C-store clobbers its slice
            const int kt = (wv + 1 + i) & 7;
            f16x8 sh[4], wh[2];
            #pragma unroll
            for (int rt = 0; rt < 4; ++rt)
                sh[rt] = BV[(kt*4 + rt)*64 + lane];
            #pragma unroll
            for (int mtj = 0; mtj < 2; ++mtj)
                wh[mtj] = *(const f16x8*)&Wb[(size_t)(kt*16 + wv*2 + mtj)*512 + lane*8];
            #pragma unroll
            for (int mtj = 0; mtj < 2; ++mtj)
                #pragma unroll
                for (int rt = 0; rt < 4; ++rt)
                    acc[mtj][rt] = __builtin_amdgcn_mfma_f32_16x16x32_f16(wh[mtj], sh[rt],
                                                                          acc[mtj][rt], 0, 0, 0);
        }

        // C frags -> wave-local fp16 zbuf (own slice wv), pk converts + b64 stores
        #pragma unroll
        for (int mtj = 0; mtj < 2; ++mtj) {
            const int jl = mtj*16 + q*4;
            #pragma unroll
            for (int rt = 0; rt < 4; ++rt) {
                const int r = rt*16 + c;
                const int h = wv*2048 + r*32 + ((jl + 4*(r&7)) & 31);
                *(f16x4_a*)&Bh[h] = cat2(pkrtz(acc[mtj][rt][0], acc[mtj][rt][1]),
                                         pkrtz(acc[mtj][rt][2], acc[mtj][rt][3]));
            }
        }
        asm volatile("s_waitcnt lgkmcnt(0)" ::: "memory");   // stores visible to own wave

        // ---- packed coupling: lane owns units wv*32+qd*4..+3, sample m ----
        {
            const float* __restrict__ bb = (l == 0) ? b1 : (l == 1) ? b2 : b3;
            float bvv[4];
            *(f32x4*)bvv = *(const f32x4*)&bb[wv*32 + qd*4];

            const int xoff = 4*((qd + m) & 7);    // rotation is s-invariant (r&7 == m)
            f16x4 zq[7];
            #pragma unroll
            for (int s = 0; s < 7; ++s)
                zq[s] = *(const f16x4_a*)&Bh[wv*2048 + (s*8 + m)*32 + xoff];

            float hf[4];
            #pragma unroll
            for (int jj = 0; jj < 4; ++jj)
                hf[jj] = tanh_fast((float)zq[0][jj] + bvv[jj]);

            f16x2 zt2[3][2], zr2[3][2];
            #pragma unroll
            for (int k = 0; k < 3; ++k) {
                zt2[k][0] = __builtin_shufflevector(zq[1+k], zq[1+k], 0, 1);
                zt2[k][1] = __builtin_shufflevector(zq[1+k], zq[1+k], 2, 3);
                zr2[k][0] = __builtin_shufflevector(zq[4+k], zq[4+k], 0, 1);
                zr2[k][1] = __builtin_shufflevector(zq[4+k], zq[4+k], 2, 3);
            }
            const f16x2 one2 = {(_Float16)1.0f,  (_Float16)1.0f};
            const f16x2 m22  = {(_Float16)-2.0f, (_Float16)-2.0f};
            f16x2 h2[2], dd2[2], qq2[2];
            #pragma unroll
            for (int p = 0; p < 2; ++p) {
                h2[p] = pkrtz(hf[2*p], hf[2*p+1]);
                const f16x2 sz = zt2[0][p] + zt2[1][p] + zt2[2][p];
                dd2[p] = one2 - h2[p]*h2[p];
                qq2[p] = m22 * h2[p] * sz;
            }
            f16x2 t2[3][2], r2[3][2];
            #pragma unroll
            for (int k = 0; k < 3; ++k)
                #pragma unroll
                for (int p = 0; p < 2; ++p) {
                    t2[k][p] = dd2[p] * zt2[k][p];
                    r2[k][p] = dd2[p] * (zr2[k][p] + qq2[p]*zt2[k][p]);
                }

            if (l < 2) {
                // write next-layer B-frags into wave's OWN k slice
                #pragma unroll
                for (int s = 0; s < 7; ++s) {
                    const int r = s*8 + m;
                    const int vid = (wv*4 + (r>>4))*64 + (qd>>1)*16 + (r & 15);
                    f16x4 v;
                    if (s == 0)      v = cat2(h2[0], h2[1]);
                    else if (s <= 3) v = cat2(t2[s-1][0], t2[s-1][1]);
                    else             v = cat2(r2[s-4][0], r2[s-4][1]);
                    *(f16x4_a*)&Bh[vid*8 + (qd&1)*4] = v;
                }
                // re-zero own slice's pad rows (32 b128 vectors, lanes 0..31)
                if (lane < 32) {
                    const int vid = (wv*4 + 3)*64 + (lane>>3)*16 + 8 + (lane&7);
                    BV[vid] = zvec8;
                }
                __syncthreads();      // B-frags ready for next GEMM
            } else {
                // fused final layer: inline contraction (no f32 state array) + butterfly
                float w4r[8];
                *(f32x4*)&w4r[0] = *(const f32x4*)&W4[(wv*32 + qd*4)*2];
                *(f32x4*)&w4r[4] = *(const f32x4*)&W4[(wv*32 + qd*4)*2 + 4];
                float p[2][7];
                #pragma unroll
                for (int s = 0; s < 7; ++s) {
                    float p0 = 0.f, p1 = 0.f;
                    #pragma unroll
                    for (int e = 0; e < 4; ++e) {
                        float se;
                        if (s == 0)      se = hf[e];
                        else if (s <= 3) se = (float)t2[s-1][e>>1][e&1];
                        else             se = (float)r2[s-4][e>>1][e&1];
                        p0 += se * w4r[e*2 + 0];
                        p1 += se * w4r[e*2 + 1];
                    }
                    p[0][s] = p0; p[1][s] = p1;
                }
                #pragma unroll
                for (int ch = 0; ch < 2; ++ch) {
                    #pragma unroll
                    for (int s = 0; s < 7; ++s) {
                        float v = p[ch][s];
                        v += __shfl_xor(v, 8);
                        v += __shfl_xor(v, 16);
                        v += __shfl_xor(v, 32);
                        p[ch][s] = v;            // sum over qd, valid in every lane
                    }
                }
                if (qd == 0) {
                    #pragma unroll
                    for (int ch = 0; ch < 2; ++ch)
                        #pragma unroll
                        for (int s = 0; s < 7; ++s)
                            redw[(ch*56 + s*8 + m)*8 + wv] = p[ch][s];
                }
                __syncthreads();      // redw fully written
            }
        }
    }

    // ---------------- output: 2 ch x 7 states x 8 samples = 112 tasks ----------------
    if (t < 112) {
        const f32x4 a = *(const f32x4*)&redw[t*8];
        const f32x4 b = *(const f32x4*)&redw[t*8 + 4];
        const float v = a[0]+a[1]+a[2]+a[3] + b[0]+b[1]+b[2]+b[3];
        const int ch = t / 56, rem = t % 56, s = rem >> 3, mm = rem & 7;
        const int n = s0 + mm;
        if (n < N) {
            const size_t N2 = (size_t)N * 2, N3 = (size_t)N * 3;
            if (s == 0)      out[(size_t)n*2 + ch] = v + b4[ch];
            else if (s <= 3) out[N2 + (size_t)ch*N3 + (size_t)n*3 + (s-1)] = v;
            else             out[N2 + 2*N3 + (size_t)ch*N3 + (size_t)n*3 + (s-4)] = v;
        }
    }
}

extern "C" void kernel_launch(void* const* d_in, const int* in_sizes, int n_in,
                              void* d_out, int out_size, void* d_ws, size_t ws_size,
                              hipStream_t stream) {
    const float* X  = (const float*)d_in[0];
    const float* W0 = (const float*)d_in[1];
    const float* b0 = (const float*)d_in[2];
    const float* W1 = (const float*)d_in[3];
    const float* b1 = (const float*)d_in[4];
    const float* W2 = (const float*)d_in[5];
    const float* b2 = (const float*)d_in[6];
    const float* W3 = (const float*)d_in[7];
    const float* b3 = (const float*)d_in[8];
    const float* W4 = (const float*)d_in[9];
    const float* b4 = (const float*)d_in[10];
    const float* lb = (const float*)d_in[11];
    const float* ub = (const float*)d_in[12];
    float* out = (float*)d_out;
    _Float16* wsw = (_Float16*)d_ws;   // needs 384 KB

    const int N = in_sizes[0] / 3;

    prep_w<<<768, 256, 0, stream>>>(W1, W2, W3, wsw);

    const int grid = (N + MSAMP - 1) / MSAMP;
    pinn_mfma<<<grid, 512, 0, stream>>>(X, W0, b0, b1, b2, b3, W4, b4, lb, ub,
                                        wsw, out, N);
}

// Round 18
// 186.879 us; speedup vs baseline: 1.0820x; 1.0820x over previous
//
#include <hip/hip_runtime.h>
#include <math.h>

typedef _Float16 f16x8 __attribute__((ext_vector_type(8)));
typedef _Float16 f16x4 __attribute__((ext_vector_type(4)));
typedef _Float16 f16x2 __attribute__((ext_vector_type(2)));
typedef float    f32x4 __attribute__((ext_vector_type(4)));
// may_alias views for the unioned LDS region (state-frags <-> per-wave fp16 zbuf)
typedef f16x8 f16x8_a __attribute__((may_alias));
typedef f16x4 f16x4_a __attribute__((may_alias));
typedef f32x4 f32x4_a __attribute__((may_alias));

#define MSAMP 8       // samples per block; state-rows: r = s*8 + m, r 56..63 pad

__device__ __forceinline__ float tanh_fast(float x) {
    // 1 - 2/(exp(2x)+1); ~1e-6 abs error (verified R7..R16)
    const float e = __expf(2.0f * x);
    return 1.0f - 2.0f * __builtin_amdgcn_rcpf(e + 1.0f);
}

// v_cvt_pkrtz_f16_f32 returns __fp16x2; bit-cast to our _Float16x2 (same repr)
__device__ __forceinline__ f16x2 pkrtz(float a, float b) {
    return __builtin_bit_cast(f16x2, __builtin_amdgcn_cvt_pkrtz(a, b));
}

__device__ __forceinline__ f16x8 cat4(f16x2 a, f16x2 b, f16x2 c, f16x2 d) {
    const f16x4 lo = __builtin_shufflevector(a, b, 0, 1, 2, 3);
    const f16x4 hi = __builtin_shufflevector(c, d, 0, 1, 2, 3);
    return __builtin_shufflevector(lo, hi, 0, 1, 2, 3, 4, 5, 6, 7);
}

__device__ __forceinline__ f16x8 pack8(const float* v) {   // 4x v_cvt_pkrtz
    return cat4(pkrtz(v[0], v[1]), pkrtz(v[2], v[3]),
                pkrtz(v[4], v[5]), pkrtz(v[6], v[7]));
}

// prep_w v2: LDS-transpose version. Output layout BIT-IDENTICAL to R12..R16:
//   wsw[((l*8+kt)*16+nt)*512 + lane*8 + jj] = (f16)W[(kt*32+(lane>>4)*8+jj)*256 + nt*16+(lane&15)]
// One block per (l,kt) slab: coalesced fp32 row loads -> LDS (stride 260 f16
// breaks bank alignment) -> fully-coalesced f16x8 fragment stores.
__global__ __launch_bounds__(256)
void prep_w(const float* __restrict__ W1, const float* __restrict__ W2,
            const float* __restrict__ W3, _Float16* __restrict__ wsw) {
    const int l = blockIdx.x >> 3, kt = blockIdx.x & 7;   // grid = 24 blocks
    const float* __restrict__ W = (l == 0) ? W1 : (l == 1) ? W2 : W3;
    __shared__ _Float16 lds[32 * 260];
    const int t = threadIdx.x;

    #pragma unroll 4
    for (int kk = 0; kk < 32; ++kk)           // coalesced: consecutive t -> consecutive n
        lds[kk * 260 + t] = (_Float16)W[(kt * 32 + kk) * 256 + t];
    __syncthreads();

    const int lane = t & 63, wq = t >> 6;     // wq = 0..3
    #pragma unroll
    for (int g = 0; g < 4; ++g) {
        const int nt = wq * 4 + g;
        f16x8 v;
        #pragma unroll
        for (int jj = 0; jj < 8; ++jj)
            v[jj] = lds[((lane >> 4) * 8 + jj) * 260 + nt * 16 + (lane & 15)];
        *(f16x8*)&wsw[((size_t)((l * 8 + kt) * 16 + nt)) * 512 + lane * 8] = v;
    }
}

// SINGLE-fp16 TRANSPOSED GEMM (R16 exact — verified 120.2 µs dispatch):
// 256 threads / 4 waves; wave wv owns jt = wv*4..+3; packed-fp16 coupling;
// rotated K (kt=(2wv+2+i)&7) with barrier at i==6; per-wave fp16 zbuf aliasing
// wave's own 2 kt slices; butterfly epilogue. launch_bounds(256,3): no spill.
// R17's 8-wave split regressed: each wave reads the WHOLE state buffer per
// layer, so halving the tile doubled GEMM LDS traffic — do not re-attempt.
__global__ __launch_bounds__(256, 3)
void pinn_mfma(const float* __restrict__ X,
               const float* __restrict__ W0, const float* __restrict__ b0,
               const float* __restrict__ b1, const float* __restrict__ b2,
               const float* __restrict__ b3,
               const float* __restrict__ W4, const float* __restrict__ b4,
               const float* __restrict__ lb, const float* __restrict__ ub,
               const _Float16* __restrict__ wsw,
               float* __restrict__ out, int N)
{
    __shared__ __attribute__((aligned(16))) char  smem[32768];   // state frags / zbuf
    __shared__ __attribute__((aligned(16))) float redw[448];     // [ch*56+s*8+m][wv]
    f16x8_a*  BV  = (f16x8_a*)smem;               // vec idx = (kt*4+rt)*64 + lane
    _Float16* zbh = (_Float16*)smem;              // per-wave fp16 zbuf view

    const int t    = threadIdx.x;
    const int s0   = blockIdx.x * MSAMP;
    const int wv   = t >> 6, lane = t & 63;
    const int q    = lane >> 4, c = lane & 15;    // C/D + B-frag coords
    const int jgl  = lane >> 3, m = lane & 7;     // coupling task (unit octet, sample)
    const int jg   = wv * 8 + jgl;                // global unit octet 0..31
    const int kt0  = jg >> 2, lq0 = jg & 3;       // B-frag k coords for jg

    const int vidz0 = ((t >> 5) * 4 + 3) * 64 + ((t >> 3) & 3) * 16 + 8 + (t & 7);
    const int vidzw = (((wv * 2 + (lane >> 5)) * 4 + 3) * 64) + (((lane >> 3) & 3) * 16) + 8 + (lane & 7);
    const f16x8 zvec = {};

    float lbv[3], cv[3];
    #pragma unroll
    for (int k = 0; k < 3; ++k) { lbv[k] = lb[k]; cv[k] = 2.0f / (ub[k] - lbv[k]); }

    // ---------------- layer 0: inputs -> first hidden states (B frags) ----------------
    {
        const int jg0 = t >> 3, m0 = t & 7;
        const int n = s0 + m0;
        float x0 = 0.f, x1 = 0.f, x2 = 0.f;
        if (n < N) { x0 = X[n*3+0]; x1 = X[n*3+1]; x2 = X[n*3+2]; }
        const float h0 = cv[0]*(x0 - lbv[0]) - 1.0f;
        const float h1 = cv[1]*(x1 - lbv[1]) - 1.0f;
        const float h2 = cv[2]*(x2 - lbv[2]) - 1.0f;

        float w0v[8], w1v[8], w2v[8], bv[8];
        *(f32x4*)&w0v[0] = *(const f32x4*)&W0[0*256 + jg0*8];
        *(f32x4*)&w0v[4] = *(const f32x4*)&W0[0*256 + jg0*8 + 4];
        *(f32x4*)&w1v[0] = *(const f32x4*)&W0[1*256 + jg0*8];
        *(f32x4*)&w1v[4] = *(const f32x4*)&W0[1*256 + jg0*8 + 4];
        *(f32x4*)&w2v[0] = *(const f32x4*)&W0[2*256 + jg0*8];
        *(f32x4*)&w2v[4] = *(const f32x4*)&W0[2*256 + jg0*8 + 4];
        *(f32x4*)&bv[0]  = *(const f32x4*)&b0[jg0*8];
        *(f32x4*)&bv[4]  = *(const f32x4*)&b0[jg0*8 + 4];

        float st[7][8];
        #pragma unroll
        for (int jj = 0; jj < 8; ++jj) {
            const float zH  = h0*w0v[jj] + h1*w1v[jj] + h2*w2v[jj] + bv[jj];
            const float zt0 = cv[0]*w0v[jj];
            const float zt1 = cv[1]*w1v[jj];
            const float zt2 = cv[2]*w2v[jj];
            const float h   = tanh_fast(zH);
            const float dd  = 1.0f - h*h;
            const float qq  = -2.0f * h * (zt0 + zt1 + zt2);
            st[0][jj] = h;
            st[1][jj] = dd * zt0; st[2][jj] = dd * zt1; st[3][jj] = dd * zt2;
            st[4][jj] = dd * (qq*zt0); st[5][jj] = dd * (qq*zt1); st[6][jj] = dd * (qq*zt2);
        }
        const int k0a = jg0 >> 2, l0a = jg0 & 3;
        #pragma unroll
        for (int s = 0; s < 7; ++s) {
            const int r = s*8 + m0;
            BV[(k0a*4 + (r>>4))*64 + l0a*16 + (r & 15)] = pack8(&st[s][0]);
        }
        BV[vidz0] = zvec;     // zero pad rows r = 56..63
    }
    __syncthreads();

    // ---------------- hidden layers: rotated-K GEMM + packed wave-local coupling ----------------
    #pragma unroll 1
    for (int l = 0; l < 3; ++l) {
        const _Float16* __restrict__ Wb = wsw + (size_t)l * 65536;
        const int ktbase = 2*wv + 2;

        f32x4 acc[4][4];   // [mtj][rt]
        #pragma unroll
        for (int a = 0; a < 4; ++a)
            #pragma unroll
            for (int b = 0; b < 4; ++b) acc[a][b] = (f32x4){0.f, 0.f, 0.f, 0.f};

        #pragma unroll
        for (int i = 0; i < 8; ++i) {
            if (i == 6) __syncthreads();   // all foreign-slice reads done before any
                                           // wave's zbuf can clobber its own slices
            const int kt = (ktbase + i) & 7;
            f16x8 sh[4], wh[4];
            #pragma unroll
            for (int rt = 0; rt < 4; ++rt)
                sh[rt] = BV[(kt*4 + rt)*64 + lane];
            #pragma unroll
            for (int mtj = 0; mtj < 4; ++mtj)
                wh[mtj] = *(const f16x8*)&Wb[(size_t)(kt*16 + wv*4 + mtj)*512 + lane*8];
            #pragma unroll
            for (int mtj = 0; mtj < 4; ++mtj)
                #pragma unroll
                for (int rt = 0; rt < 4; ++rt)
                    acc[mtj][rt] = __builtin_amdgcn_mfma_f32_16x16x32_f16(wh[mtj], sh[rt],
                                                                          acc[mtj][rt], 0, 0, 0);
        }

        // C frags -> wave-local fp16 zbuf (own slices only), pk converts + b64 stores
        #pragma unroll
        for (int mtj = 0; mtj < 4; ++mtj) {
            const int jl = mtj*16 + q*4;
            #pragma unroll
            for (int rt = 0; rt < 4; ++rt) {
                const int r = rt*16 + c;
                const int h = wv*4096 + r*64 + ((jl + 4*(r&15)) & 63);
                const f16x2 plo = pkrtz(acc[mtj][rt][0], acc[mtj][rt][1]);
                const f16x2 phi = pkrtz(acc[mtj][rt][2], acc[mtj][rt][3]);
                *(f16x4_a*)&zbh[h] = __builtin_shufflevector(plo, phi, 0, 1, 2, 3);
            }
        }
        asm volatile("s_waitcnt lgkmcnt(0)" ::: "memory");   // stores visible to own wave

        // ---- packed coupling: lane owns (jg, m) ----
        {
            const float* __restrict__ bb = (l == 0) ? b1 : (l == 1) ? b2 : b3;
            float bvv[8];
            *(f32x4*)&bvv[0] = *(const f32x4*)&bb[jg*8];
            *(f32x4*)&bvv[4] = *(const f32x4*)&bb[jg*8 + 4];

            f16x4 zlo[7], zhi[7];
            #pragma unroll
            for (int s = 0; s < 7; ++s) {
                const int r    = s*8 + m;
                const int base = wv*4096 + r*64;
                const int rot  = 4*(r & 15);
                zlo[s] = *(const f16x4_a*)&zbh[base + ((jgl*8     + rot) & 63)];
                zhi[s] = *(const f16x4_a*)&zbh[base + ((jgl*8 + 4 + rot) & 63)];
            }

            // tanh path in f32 (8 values)
            float hf[8];
            #pragma unroll
            for (int jj = 0; jj < 8; ++jj) {
                const float z0 = (jj < 4) ? (float)zlo[0][jj] : (float)zhi[0][jj-4];
                hf[jj] = tanh_fast(z0 + bvv[jj]);
            }

            // packed pairs (p = 0..3 <-> units 2p, 2p+1)
            f16x2 zt2[3][4], zr2[3][4];
            #pragma unroll
            for (int k = 0; k < 3; ++k) {
                zt2[k][0] = __builtin_shufflevector(zlo[1+k], zlo[1+k], 0, 1);
                zt2[k][1] = __builtin_shufflevector(zlo[1+k], zlo[1+k], 2, 3);
                zt2[k][2] = __builtin_shufflevector(zhi[1+k], zhi[1+k], 0, 1);
                zt2[k][3] = __builtin_shufflevector(zhi[1+k], zhi[1+k], 2, 3);
                zr2[k][0] = __builtin_shufflevector(zlo[4+k], zlo[4+k], 0, 1);
                zr2[k][1] = __builtin_shufflevector(zlo[4+k], zlo[4+k], 2, 3);
                zr2[k][2] = __builtin_shufflevector(zhi[4+k], zhi[4+k], 0, 1);
                zr2[k][3] = __builtin_shufflevector(zhi[4+k], zhi[4+k], 2, 3);
            }
            const f16x2 one2 = {(_Float16)1.0f,  (_Float16)1.0f};
            const f16x2 m22  = {(_Float16)-2.0f, (_Float16)-2.0f};
            f16x2 h2[4], dd2[4], qq2[4];
            #pragma unroll
            for (int p = 0; p < 4; ++p) {
                h2[p] = pkrtz(hf[2*p], hf[2*p+1]);
                const f16x2 sz = zt2[0][p] + zt2[1][p] + zt2[2][p];
                dd2[p] = one2 - h2[p]*h2[p];
                qq2[p] = m22 * h2[p] * sz;
            }
            f16x2 t2[3][4], r2[3][4];
            #pragma unroll
            for (int k = 0; k < 3; ++k)
                #pragma unroll
                for (int p = 0; p < 4; ++p) {
                    t2[k][p] = dd2[p] * zt2[k][p];
                    r2[k][p] = dd2[p] * (zr2[k][p] + qq2[p]*zt2[k][p]);
                }

            if (l < 2) {
                // B-frag writes: results already f16, zero conversions
                #pragma unroll
                for (int s = 0; s < 7; ++s) {
                    const int r = s*8 + m;
                    const int vid = (kt0*4 + (r>>4))*64 + lq0*16 + (r & 15);
                    f16x8 v;
                    if (s == 0)      v = cat4(h2[0], h2[1], h2[2], h2[3]);
                    else if (s <= 3) v = cat4(t2[s-1][0], t2[s-1][1], t2[s-1][2], t2[s-1][3]);
                    else             v = cat4(r2[s-4][0], r2[s-4][1], r2[s-4][2], r2[s-4][3]);
                    BV[vid] = v;
                }
                BV[vidzw] = zvec;     // re-zero wave's pad rows r=56..63
                __syncthreads();      // B-frags ready for next GEMM
            } else {
                // fused final layer (once): unpack to f32, W4 contraction + butterfly
                float sttf[7][8];
                #pragma unroll
                for (int jj = 0; jj < 8; ++jj) sttf[0][jj] = hf[jj];
                #pragma unroll
                for (int k = 0; k < 3; ++k)
                    #pragma unroll
                    for (int p = 0; p < 4; ++p) {
                        sttf[1+k][2*p]   = (float)t2[k][p][0];
                        sttf[1+k][2*p+1] = (float)t2[k][p][1];
                        sttf[4+k][2*p]   = (float)r2[k][p][0];
                        sttf[4+k][2*p+1] = (float)r2[k][p][1];
                    }
                float w4r[16];
                #pragma unroll
                for (int q4 = 0; q4 < 4; ++q4)
                    *(f32x4*)&w4r[q4*4] = *(const f32x4*)&W4[jg*16 + q4*4];
                float p[2][7];
                #pragma unroll
                for (int s = 0; s < 7; ++s) {
                    float p0 = 0.f, p1 = 0.f;
                    #pragma unroll
                    for (int jj = 0; jj < 8; ++jj) {
                        p0 += sttf[s][jj] * w4r[jj*2 + 0];
                        p1 += sttf[s][jj] * w4r[jj*2 + 1];
                    }
                    p[0][s] = p0; p[1][s] = p1;
                }
                #pragma unroll
                for (int ch = 0; ch < 2; ++ch) {
                    #pragma unroll
                    for (int s = 0; s < 7; ++s) {
                        float v = p[ch][s];
                        v += __shfl_xor(v, 8);
                        v += __shfl_xor(v, 16);
                        v += __shfl_xor(v, 32);
                        p[ch][s] = v;            // sum over jgl, valid in every lane
                    }
                }
                if (jgl == 0) {
                    #pragma unroll
                    for (int ch = 0; ch < 2; ++ch)
                        #pragma unroll
                        for (int s = 0; s < 7; ++s)
                            redw[(ch*56 + s*8 + m)*4 + wv] = p[ch][s];
                }
                __syncthreads();      // redw fully written
            }
        }
    }

    // ---------------- output: 2 ch x 7 states x 8 samples = 112 tasks ----------------
    if (t < 112) {
        const f32x4 vv = *(const f32x4*)&redw[t*4];   // 4 wave partials
        const float v = vv[0] + vv[1] + vv[2] + vv[3];
        const int ch = t / 56, rem = t % 56, s = rem >> 3, mm = rem & 7;
        const int n = s0 + mm;
        if (n < N) {
            const size_t N2 = (size_t)N * 2, N3 = (size_t)N * 3;
            if (s == 0)      out[(size_t)n*2 + ch] = v + b4[ch];
            else if (s <= 3) out[N2 + (size_t)ch*N3 + (size_t)n*3 + (s-1)] = v;
            else             out[N2 + 2*N3 + (size_t)ch*N3 + (size_t)n*3 + (s-4)] = v;
        }
    }
}

extern "C" void kernel_launch(void* const* d_in, const int* in_sizes, int n_in,
                              void* d_out, int out_size, void* d_ws, size_t ws_size,
                              hipStream_t stream) {
    const float* X  = (const float*)d_in[0];
    const float* W0 = (const float*)d_in[1];
    const float* b0 = (const float*)d_in[2];
    const float* W1 = (const float*)d_in[3];
    const float* b1 = (const float*)d_in[4];
    const float* W2 = (const float*)d_in[5];
    const float* b2 = (const float*)d_in[6];
    const float* W3 = (const float*)d_in[7];
    const float* b3 = (const float*)d_in[8];
    const float* W4 = (const float*)d_in[9];
    const float* b4 = (const float*)d_in[10];
    const float* lb = (const float*)d_in[11];
    const float* ub = (const float*)d_in[12];
    float* out = (float*)d_out;
    _Float16* wsw = (_Float16*)d_ws;   // needs 384 KB

    const int N = in_sizes[0] / 3;

    prep_w<<<24, 256, 0, stream>>>(W1, W2, W3, wsw);

    const int grid = (N + MSAMP - 1) / MSAMP;
    pinn_mfma<<<grid, 256, 0, stream>>>(X, W0, b0, b1, b2, b3, W4, b4, lb, ub,
                                        wsw, out, N);
}